// Round 2
// baseline (884.989 us; speedup 1.0000x reference)
//
#include <hip/hip_runtime.h>
#include <stdint.h>

// ---------------- helpers ----------------

__global__ void k_zero(int* __restrict__ p, int n) {
    int i = blockIdx.x * blockDim.x + threadIdx.x;
    if (i < n) p[i] = 0;
}

// deg[v] = number of edges with dst==v  (self loop added later as +1)
__global__ void k_count(const int* __restrict__ dst, int E, int* __restrict__ deg) {
    for (int e = blockIdx.x * blockDim.x + threadIdx.x; e < E; e += gridDim.x * blockDim.x)
        atomicAdd(&deg[dst[e]], 1);
}

__global__ void k_dinv(const int* __restrict__ deg, float* __restrict__ dinv, int n) {
    int i = blockIdx.x * blockDim.x + threadIdx.x;
    if (i < n) dinv[i] = rsqrtf((float)(deg[i] + 1));   // +1 = self loop
}

// -------- 2-level exclusive scan over deg (n=100000, tiles of 256) --------

__global__ void k_scan_blocks(const int* __restrict__ deg, int n,
                              int* __restrict__ part, int* __restrict__ tile_sums) {
    __shared__ int s[256];
    int t = threadIdx.x;
    int i = blockIdx.x * 256 + t;
    int v = (i < n) ? deg[i] : 0;
    s[t] = v;
    __syncthreads();
    for (int off = 1; off < 256; off <<= 1) {
        int x = (t >= off) ? s[t - off] : 0;
        __syncthreads();
        s[t] += x;
        __syncthreads();
    }
    if (i < n) part[i] = s[t] - v;          // exclusive within tile
    if (t == 255) tile_sums[blockIdx.x] = s[255];
}

__global__ void k_scan_tiles(int* __restrict__ tile_sums, int ntiles) {
    __shared__ int s[512];
    int t = threadIdx.x;
    int v = (t < ntiles) ? tile_sums[t] : 0;
    s[t] = v;
    __syncthreads();
    for (int off = 1; off < 512; off <<= 1) {
        int x = (t >= off) ? s[t - off] : 0;
        __syncthreads();
        s[t] += x;
        __syncthreads();
    }
    if (t < ntiles) tile_sums[t] = s[t] - v;  // exclusive tile offsets
}

__global__ void k_scan_add(int* __restrict__ offsets, const int* __restrict__ tile_sums,
                           int n, int E, int* __restrict__ cursor) {
    int i = blockIdx.x * 256 + threadIdx.x;
    if (i < n) {
        int o = offsets[i] + tile_sums[blockIdx.x];
        offsets[i] = o;
        cursor[i]  = o;
    }
    if (i == 0) offsets[n] = E;
}

__global__ void k_fill(const int* __restrict__ src, const int* __restrict__ dst,
                       int E, int* __restrict__ cursor, int* __restrict__ csr_src) {
    for (int e = blockIdx.x * blockDim.x + threadIdx.x; e < E; e += gridDim.x * blockDim.x) {
        int d = dst[e];
        int pos = atomicAdd(&cursor[d], 1);
        csr_src[pos] = src[e];
    }
}

// ---------------- GEMM: C[n x 128] = A[n x 128] @ W[128 x 128], fp32 ----------------
// W fully in LDS (64 KB); 32-row x-tile in LDS (16 KB); 4x4 register tiles.
#define COMP(v, i) ((i) == 0 ? (v).x : (i) == 1 ? (v).y : (i) == 2 ? (v).z : (v).w)

__global__ __launch_bounds__(256) void k_gemm128(const float* __restrict__ A,
                                                 const float* __restrict__ W,
                                                 float* __restrict__ C, int ntiles32) {
    __shared__ float wl[128 * 128];
    __shared__ float xl[32 * 128];
    int t = threadIdx.x;
#pragma unroll
    for (int i = 0; i < 16; i++)
        ((float4*)wl)[t + 256 * i] = ((const float4*)W)[t + 256 * i];

    int jg = t & 31;   // column group: cols 4*jg .. 4*jg+3
    int rg = t >> 5;   // row group: rows rg*4 .. rg*4+3 within tile

    for (int tile = blockIdx.x; tile < ntiles32; tile += gridDim.x) {
        const float4* Ap = (const float4*)(A + (size_t)tile * 32 * 128);
        __syncthreads();   // protects xl (prev iter) and wl (first iter)
#pragma unroll
        for (int i = 0; i < 4; i++)
            ((float4*)xl)[t + 256 * i] = Ap[t + 256 * i];
        __syncthreads();

        float acc[4][4];
#pragma unroll
        for (int r = 0; r < 4; r++)
#pragma unroll
            for (int c = 0; c < 4; c++) acc[r][c] = 0.f;

        for (int kc = 0; kc < 128; kc += 4) {
            float4 xa[4], wb[4];
#pragma unroll
            for (int r = 0; r < 4; r++)
                xa[r] = ((const float4*)xl)[((rg * 4 + r) * 128 + kc) >> 2];
#pragma unroll
            for (int kk = 0; kk < 4; kk++)
                wb[kk] = ((const float4*)wl)[((kc + kk) * 128 + jg * 4) >> 2];
#pragma unroll
            for (int kk = 0; kk < 4; kk++) {
#pragma unroll
                for (int r = 0; r < 4; r++) {
                    float xv = COMP(xa[r], kk);
                    acc[r][0] = fmaf(xv, wb[kk].x, acc[r][0]);
                    acc[r][1] = fmaf(xv, wb[kk].y, acc[r][1]);
                    acc[r][2] = fmaf(xv, wb[kk].z, acc[r][2]);
                    acc[r][3] = fmaf(xv, wb[kk].w, acc[r][3]);
                }
            }
        }

        float4* Cp = (float4*)(C + (size_t)tile * 32 * 128);
#pragma unroll
        for (int r = 0; r < 4; r++)
            Cp[(rg * 4 + r) * 32 + jg] = make_float4(acc[r][0], acc[r][1], acc[r][2], acc[r][3]);
    }
}

// ---------------- Aggregation: out[v] = relu(dinv[v]*(sum_e dinv[u]*xw[u] + dinv[v]*xw[v]) + b) --------
__global__ __launch_bounds__(128) void k_agg(const float* __restrict__ xw,
                                             const int* __restrict__ offsets,
                                             const int* __restrict__ csr,
                                             const float* __restrict__ dinv,
                                             const float* __restrict__ bias,
                                             float* __restrict__ out, int n) {
    int j = threadIdx.x;
    float bj = bias[j];
    for (int v = blockIdx.x; v < n; v += gridDim.x) {
        float dv = dinv[v];
        float acc = dv * xw[(size_t)v * 128 + j];   // self loop (dv^2 after final *dv)
        int e0 = offsets[v], e1 = offsets[v + 1];
        for (int e = e0; e < e1; e++) {
            int u = csr[e];
            acc += dinv[u] * xw[(size_t)u * 128 + j];
        }
        out[(size_t)v * 128 + j] = fmaxf(fmaf(acc, dv, bj), 0.f);
    }
}

// ---------------- Mean pool + FC ----------------
__global__ __launch_bounds__(128) void k_pool(const float* __restrict__ h,
                                              float* __restrict__ pooled, int n) {
    int j = threadIdx.x;
    float local = 0.f;
    for (int r = blockIdx.x; r < n; r += gridDim.x)
        local += h[(size_t)r * 128 + j];
    atomicAdd(&pooled[j], local);
}

__global__ __launch_bounds__(128) void k_fc(const float* __restrict__ pooled,
                                            const float* __restrict__ Wfc,
                                            const float* __restrict__ bfc,
                                            float* __restrict__ out, float invN) {
    int j = threadIdx.x;
    float acc = bfc[j];
    for (int k = 0; k < 128; k++)
        acc = fmaf(pooled[k] * invN, Wfc[k * 128 + j], acc);
    out[j] = acc;
}

// ---------------- launcher ----------------
extern "C" void kernel_launch(void* const* d_in, const int* in_sizes, int n_in,
                              void* d_out, int out_size, void* d_ws, size_t ws_size,
                              hipStream_t stream) {
    const float* x    = (const float*)d_in[0];
    const int*   ei   = (const int*)d_in[1];     // harness delivers integer inputs as int32
    const float* W1   = (const float*)d_in[2];
    const float* b1   = (const float*)d_in[3];
    const float* W2   = (const float*)d_in[4];
    const float* b2   = (const float*)d_in[5];
    const float* Wfc  = (const float*)d_in[6];
    const float* bfc  = (const float*)d_in[7];
    float*       out  = (float*)d_out;

    const int n = in_sizes[0] / 128;
    const int E = in_sizes[1] / 2;
    const int* src = ei;
    const int* dst = ei + E;

    char* w = (char*)d_ws;
    float* xw   = (float*)w;  w += (size_t)n * 128 * sizeof(float);
    float* h    = (float*)w;  w += (size_t)n * 128 * sizeof(float);
    int*   csr  = (int*)w;    w += (size_t)E * sizeof(int);
    float* dinv = (float*)w;  w += (size_t)n * sizeof(float);
    int*   deg  = (int*)w;    w += (size_t)n * sizeof(int);
    int*   offs = (int*)w;    w += (size_t)(n + 1) * sizeof(int);
    w = (char*)(((uintptr_t)w + 15) & ~(uintptr_t)15);
    int*   cursor = (int*)w;  w += (size_t)n * sizeof(int);
    int*   tiles  = (int*)w;  w += 512 * sizeof(int);
    float* pooled = (float*)w; w += 128 * sizeof(float);

    const int ntiles = (n + 255) / 256;

    k_zero<<<(n + 255) / 256, 256, 0, stream>>>(deg, n);
    k_zero<<<1, 128, 0, stream>>>((int*)pooled, 128);
    k_count<<<1024, 256, 0, stream>>>(dst, E, deg);
    k_dinv<<<(n + 255) / 256, 256, 0, stream>>>(deg, dinv, n);
    k_scan_blocks<<<ntiles, 256, 0, stream>>>(deg, n, offs, tiles);
    k_scan_tiles<<<1, 512, 0, stream>>>(tiles, ntiles);
    k_scan_add<<<ntiles, 256, 0, stream>>>(offs, tiles, n, E, cursor);
    k_fill<<<1024, 256, 0, stream>>>(src, dst, E, cursor, csr);

    k_gemm128<<<512, 256, 0, stream>>>(x, W1, xw, n / 32);
    k_agg<<<8192, 128, 0, stream>>>(xw, offs, csr, dinv, b1, h, n);
    k_gemm128<<<512, 256, 0, stream>>>(h, W2, xw, n / 32);
    k_agg<<<8192, 128, 0, stream>>>(xw, offs, csr, dinv, b2, h, n);

    k_pool<<<512, 128, 0, stream>>>(h, pooled, n);
    k_fc<<<1, 128, 0, stream>>>(pooled, Wfc, bfc, out, 1.0f / (float)n);
}

// Round 3
// 612.124 us; speedup vs baseline: 1.4458x; 1.4458x over previous
//
#include <hip/hip_runtime.h>
#include <stdint.h>

typedef unsigned short ushort_t;

// ---------------- helpers ----------------

__global__ void k_zero(int* __restrict__ p, int n) {
    int i = blockIdx.x * blockDim.x + threadIdx.x;
    if (i < n) p[i] = 0;
}

// deg[v] = number of edges with dst==v  (self loop added later as +1)
__global__ void k_count(const int* __restrict__ dst, int E, int* __restrict__ deg) {
    for (int e = blockIdx.x * blockDim.x + threadIdx.x; e < E; e += gridDim.x * blockDim.x)
        atomicAdd(&deg[dst[e]], 1);
}

__global__ void k_dinv(const int* __restrict__ deg, float* __restrict__ dinv, int n) {
    int i = blockIdx.x * blockDim.x + threadIdx.x;
    if (i < n) dinv[i] = rsqrtf((float)(deg[i] + 1));   // +1 = self loop
}

// -------- 2-level exclusive scan over deg (n=100000, tiles of 256) --------

__global__ void k_scan_blocks(const int* __restrict__ deg, int n,
                              int* __restrict__ part, int* __restrict__ tile_sums) {
    __shared__ int s[256];
    int t = threadIdx.x;
    int i = blockIdx.x * 256 + t;
    int v = (i < n) ? deg[i] : 0;
    s[t] = v;
    __syncthreads();
    for (int off = 1; off < 256; off <<= 1) {
        int x = (t >= off) ? s[t - off] : 0;
        __syncthreads();
        s[t] += x;
        __syncthreads();
    }
    if (i < n) part[i] = s[t] - v;          // exclusive within tile
    if (t == 255) tile_sums[blockIdx.x] = s[255];
}

__global__ void k_scan_tiles(int* __restrict__ tile_sums, int ntiles) {
    __shared__ int s[512];
    int t = threadIdx.x;
    int v = (t < ntiles) ? tile_sums[t] : 0;
    s[t] = v;
    __syncthreads();
    for (int off = 1; off < 512; off <<= 1) {
        int x = (t >= off) ? s[t - off] : 0;
        __syncthreads();
        s[t] += x;
        __syncthreads();
    }
    if (t < ntiles) tile_sums[t] = s[t] - v;  // exclusive tile offsets
}

__global__ void k_scan_add(int* __restrict__ offsets, const int* __restrict__ tile_sums,
                           int n, int E, int* __restrict__ cursor) {
    int i = blockIdx.x * 256 + threadIdx.x;
    if (i < n) {
        int o = offsets[i] + tile_sums[blockIdx.x];
        offsets[i] = o;
        cursor[i]  = o;
    }
    if (i == 0) offsets[n] = E;
}

__global__ void k_fill(const int* __restrict__ src, const int* __restrict__ dst,
                       int E, int* __restrict__ cursor, int* __restrict__ csr_src) {
    for (int e = blockIdx.x * blockDim.x + threadIdx.x; e < E; e += gridDim.x * blockDim.x) {
        int d = dst[e];
        int pos = atomicAdd(&cursor[d], 1);
        csr_src[pos] = src[e];
    }
}

// ---------------- fp32 -> bf16 (RTN-even) ----------------
__device__ __forceinline__ ushort_t f2bf(float f) {
    union { float f; uint32_t u; } a; a.f = f;
    uint32_t u = a.u;
    uint32_t r = (u + 0x7FFFu + ((u >> 16) & 1u)) >> 16;
    return (ushort_t)r;
}
__device__ __forceinline__ float bf_lo(uint32_t p) { return __uint_as_float(p << 16); }
__device__ __forceinline__ float bf_hi(uint32_t p) { return __uint_as_float(p & 0xFFFF0000u); }

// ---------------- GEMM: C[n x 128](bf16) = A[n x 128](f32) @ W[128 x 128](f32) ----------
// W fully in LDS (64 KB); 32-row x-tile in LDS (16 KB); 4x4 register tiles.
#define COMP(v, i) ((i) == 0 ? (v).x : (i) == 1 ? (v).y : (i) == 2 ? (v).z : (v).w)

__global__ __launch_bounds__(256) void k_gemm128(const float* __restrict__ A,
                                                 const float* __restrict__ W,
                                                 ushort_t* __restrict__ C, int ntiles32) {
    __shared__ float wl[128 * 128];
    __shared__ float xl[32 * 128];
    int t = threadIdx.x;
#pragma unroll
    for (int i = 0; i < 16; i++)
        ((float4*)wl)[t + 256 * i] = ((const float4*)W)[t + 256 * i];

    int jg = t & 31;   // column group: cols 4*jg .. 4*jg+3
    int rg = t >> 5;   // row group: rows rg*4 .. rg*4+3 within tile

    for (int tile = blockIdx.x; tile < ntiles32; tile += gridDim.x) {
        const float4* Ap = (const float4*)(A + (size_t)tile * 32 * 128);
        __syncthreads();   // protects xl (prev iter) and wl (first iter)
#pragma unroll
        for (int i = 0; i < 4; i++)
            ((float4*)xl)[t + 256 * i] = Ap[t + 256 * i];
        __syncthreads();

        float acc[4][4];
#pragma unroll
        for (int r = 0; r < 4; r++)
#pragma unroll
            for (int c = 0; c < 4; c++) acc[r][c] = 0.f;

        for (int kc = 0; kc < 128; kc += 4) {
            float4 xa[4], wb[4];
#pragma unroll
            for (int r = 0; r < 4; r++)
                xa[r] = ((const float4*)xl)[((rg * 4 + r) * 128 + kc) >> 2];
#pragma unroll
            for (int kk = 0; kk < 4; kk++)
                wb[kk] = ((const float4*)wl)[((kc + kk) * 128 + jg * 4) >> 2];
#pragma unroll
            for (int kk = 0; kk < 4; kk++) {
#pragma unroll
                for (int r = 0; r < 4; r++) {
                    float xv = COMP(xa[r], kk);
                    acc[r][0] = fmaf(xv, wb[kk].x, acc[r][0]);
                    acc[r][1] = fmaf(xv, wb[kk].y, acc[r][1]);
                    acc[r][2] = fmaf(xv, wb[kk].z, acc[r][2]);
                    acc[r][3] = fmaf(xv, wb[kk].w, acc[r][3]);
                }
            }
        }

        // pack fp32 -> bf16, store 8B per (row, col-group)
#pragma unroll
        for (int r = 0; r < 4; r++) {
            ushort4 us;
            us.x = f2bf(acc[r][0]); us.y = f2bf(acc[r][1]);
            us.z = f2bf(acc[r][2]); us.w = f2bf(acc[r][3]);
            ((ushort4*)(C + ((size_t)tile * 32 + rg * 4 + r) * 128))[jg] = us;
        }
    }
}

// ---------------- Aggregation (wave-per-node, bf16 gather, fp32 accumulate) ----------------
// out[v][c] = relu( dv * ( dv*xw[v][c] + sum_e dinv[u]*xw[u][c] ) + b[c] )
// lane l owns channels 2l, 2l+1 (one bf16x2 dword of the 256B row).
__global__ __launch_bounds__(256) void k_agg(const ushort_t* __restrict__ xw,
                                             const int* __restrict__ offsets,
                                             const int* __restrict__ csr,
                                             const float* __restrict__ dinv,
                                             const float* __restrict__ bias,
                                             float* __restrict__ out, int n) {
    const int l = threadIdx.x & 63;
    const int wave = (blockIdx.x << 2) | (threadIdx.x >> 6);
    const int wstride = gridDim.x << 2;
    const float2 bb = ((const float2*)bias)[l];

    for (int v = wave; v < n; v += wstride) {
        float dv = dinv[v];
        uint32_t pv = ((const uint32_t*)(xw + (size_t)v * 128))[l];
        float ax = dv * bf_lo(pv);
        float ay = dv * bf_hi(pv);

        int e = offsets[v], e1 = offsets[v + 1];
        for (; e + 3 < e1; e += 4) {
            int u0 = csr[e], u1 = csr[e + 1], u2 = csr[e + 2], u3 = csr[e + 3];
            float d0 = dinv[u0], d1 = dinv[u1], d2 = dinv[u2], d3 = dinv[u3];
            uint32_t p0 = ((const uint32_t*)(xw + (size_t)u0 * 128))[l];
            uint32_t p1 = ((const uint32_t*)(xw + (size_t)u1 * 128))[l];
            uint32_t p2 = ((const uint32_t*)(xw + (size_t)u2 * 128))[l];
            uint32_t p3 = ((const uint32_t*)(xw + (size_t)u3 * 128))[l];
            ax = fmaf(d0, bf_lo(p0), ax); ay = fmaf(d0, bf_hi(p0), ay);
            ax = fmaf(d1, bf_lo(p1), ax); ay = fmaf(d1, bf_hi(p1), ay);
            ax = fmaf(d2, bf_lo(p2), ax); ay = fmaf(d2, bf_hi(p2), ay);
            ax = fmaf(d3, bf_lo(p3), ax); ay = fmaf(d3, bf_hi(p3), ay);
        }
        for (; e < e1; e++) {
            int u = csr[e];
            float du = dinv[u];
            uint32_t p = ((const uint32_t*)(xw + (size_t)u * 128))[l];
            ax = fmaf(du, bf_lo(p), ax); ay = fmaf(du, bf_hi(p), ay);
        }

        float2 o;
        o.x = fmaxf(fmaf(ax, dv, bb.x), 0.f);
        o.y = fmaxf(fmaf(ay, dv, bb.y), 0.f);
        ((float2*)(out + (size_t)v * 128))[l] = o;
    }
}

// ---------------- Mean pool + FC ----------------
__global__ __launch_bounds__(128) void k_pool(const float* __restrict__ h,
                                              float* __restrict__ pooled, int n) {
    int j = threadIdx.x;
    float local = 0.f;
    for (int r = blockIdx.x; r < n; r += gridDim.x)
        local += h[(size_t)r * 128 + j];
    atomicAdd(&pooled[j], local);
}

__global__ __launch_bounds__(128) void k_fc(const float* __restrict__ pooled,
                                            const float* __restrict__ Wfc,
                                            const float* __restrict__ bfc,
                                            float* __restrict__ out, float invN) {
    int j = threadIdx.x;
    float acc = bfc[j];
    for (int k = 0; k < 128; k++)
        acc = fmaf(pooled[k] * invN, Wfc[k * 128 + j], acc);
    out[j] = acc;
}

// ---------------- launcher ----------------
extern "C" void kernel_launch(void* const* d_in, const int* in_sizes, int n_in,
                              void* d_out, int out_size, void* d_ws, size_t ws_size,
                              hipStream_t stream) {
    const float* x    = (const float*)d_in[0];
    const int*   ei   = (const int*)d_in[1];     // harness delivers integer inputs as int32
    const float* W1   = (const float*)d_in[2];
    const float* b1   = (const float*)d_in[3];
    const float* W2   = (const float*)d_in[4];
    const float* b2   = (const float*)d_in[5];
    const float* Wfc  = (const float*)d_in[6];
    const float* bfc  = (const float*)d_in[7];
    float*       out  = (float*)d_out;

    const int n = in_sizes[0] / 128;
    const int E = in_sizes[1] / 2;
    const int* src = ei;
    const int* dst = ei + E;

    char* w = (char*)d_ws;
    ushort_t* xw = (ushort_t*)w; w += (size_t)n * 128 * sizeof(ushort_t);
    w = (char*)(((uintptr_t)w + 15) & ~(uintptr_t)15);
    float* h    = (float*)w;  w += (size_t)n * 128 * sizeof(float);
    int*   csr  = (int*)w;    w += (size_t)E * sizeof(int);
    float* dinv = (float*)w;  w += (size_t)n * sizeof(float);
    int*   deg  = (int*)w;    w += (size_t)n * sizeof(int);
    int*   offs = (int*)w;    w += (size_t)(n + 1) * sizeof(int);
    w = (char*)(((uintptr_t)w + 15) & ~(uintptr_t)15);
    int*   cursor = (int*)w;  w += (size_t)n * sizeof(int);
    int*   tiles  = (int*)w;  w += 512 * sizeof(int);
    float* pooled = (float*)w; w += 128 * sizeof(float);

    const int ntiles = (n + 255) / 256;

    k_zero<<<(n + 255) / 256, 256, 0, stream>>>(deg, n);
    k_zero<<<1, 128, 0, stream>>>((int*)pooled, 128);
    k_count<<<1024, 256, 0, stream>>>(dst, E, deg);
    k_dinv<<<(n + 255) / 256, 256, 0, stream>>>(deg, dinv, n);
    k_scan_blocks<<<ntiles, 256, 0, stream>>>(deg, n, offs, tiles);
    k_scan_tiles<<<1, 512, 0, stream>>>(tiles, ntiles);
    k_scan_add<<<ntiles, 256, 0, stream>>>(offs, tiles, n, E, cursor);
    k_fill<<<1024, 256, 0, stream>>>(src, dst, E, cursor, csr);

    k_gemm128<<<512, 256, 0, stream>>>(x, W1, xw, n / 32);
    k_agg<<<8192, 256, 0, stream>>>(xw, offs, csr, dinv, b1, h, n);
    k_gemm128<<<512, 256, 0, stream>>>(h, W2, xw, n / 32);
    k_agg<<<8192, 256, 0, stream>>>(xw, offs, csr, dinv, b2, h, n);

    k_pool<<<512, 128, 0, stream>>>(h, pooled, n);
    k_fc<<<1, 128, 0, stream>>>(pooled, Wfc, bfc, out, 1.0f / (float)n);
}

// Round 4
// 516.721 us; speedup vs baseline: 1.7127x; 1.1846x over previous
//
#include <hip/hip_runtime.h>
#include <stdint.h>

typedef unsigned short ushort_t;

#define BKT_SHIFT 8
#define BKT_W     256
#define NB_MAX    512
#define KB_ITERS  8            // edges per thread in kB
#define KB_CHUNK  (256 * KB_ITERS)

// ---------------- small helpers ----------------

__global__ void k_zero(int* __restrict__ p, int n) {
    int i = blockIdx.x * blockDim.x + threadIdx.x;
    if (i < n) p[i] = 0;
}

// ---------------- kA: bucket histogram ----------------
__global__ __launch_bounds__(256) void kA_hist(const int* __restrict__ dst, int E, int NB,
                                               int* __restrict__ bhist) {
    __shared__ int lh[NB_MAX];
    int t = threadIdx.x;
    for (int i = t; i < NB; i += 256) lh[i] = 0;
    __syncthreads();
    for (int e = blockIdx.x * 256 + t; e < E; e += gridDim.x * 256)
        atomicAdd(&lh[dst[e] >> BKT_SHIFT], 1);
    __syncthreads();
    for (int i = t; i < NB; i += 256)
        if (lh[i]) atomicAdd(&bhist[i], lh[i]);
}

// ---------------- kScanB: exclusive scan of bucket hist (1 block, 512 thr) ----------------
__global__ __launch_bounds__(512) void kScanB(const int* __restrict__ bhist, int NB, int E,
                                              int* __restrict__ bbase, int* __restrict__ bcur) {
    __shared__ int s[512];
    int t = threadIdx.x;
    int v = (t < NB) ? bhist[t] : 0;
    s[t] = v;
    __syncthreads();
    for (int off = 1; off < 512; off <<= 1) {
        int x = (t >= off) ? s[t - off] : 0;
        __syncthreads();
        s[t] += x;
        __syncthreads();
    }
    if (t < NB) {
        int ex = s[t] - v;
        bbase[t] = ex;
        bcur[t]  = ex;
    }
    if (t == 0) bbase[NB] = E;
}

// ---------------- kB: scatter edges into bucket-ordered arrays ----------------
__global__ __launch_bounds__(256) void kB_bucket(const int* __restrict__ src,
                                                 const int* __restrict__ dst, int E, int NB,
                                                 int* __restrict__ bcur,
                                                 int* __restrict__ bsrc, int* __restrict__ bdst) {
    __shared__ int lh[NB_MAX];
    int t = threadIdx.x;
    for (int i = t; i < NB; i += 256) lh[i] = 0;
    __syncthreads();

    int base = blockIdx.x * KB_CHUNK;
    int dreg[KB_ITERS], rank[KB_ITERS];
#pragma unroll
    for (int i = 0; i < KB_ITERS; i++) {
        int e = base + t + i * 256;
        if (e < E) {
            int d = dst[e];
            dreg[i] = d;
            rank[i] = atomicAdd(&lh[d >> BKT_SHIFT], 1);
        } else {
            dreg[i] = -1; rank[i] = 0;
        }
    }
    __syncthreads();
    // reserve a contiguous global range per touched bucket
    for (int i = t; i < NB; i += 256) {
        int c = lh[i];
        lh[i] = c ? atomicAdd(&bcur[i], c) : 0;
    }
    __syncthreads();
#pragma unroll
    for (int i = 0; i < KB_ITERS; i++) {
        int e = base + t + i * 256;
        if (dreg[i] >= 0) {
            int pos = lh[dreg[i] >> BKT_SHIFT] + rank[i];
            bdst[pos] = dreg[i];
            bsrc[pos] = src[e];
        }
    }
}

// ---------------- kC: per-bucket fused count + scan + dinv + offs + csr fill ----------------
__global__ __launch_bounds__(256) void kC_build(const int* __restrict__ bsrc,
                                                const int* __restrict__ bdst,
                                                const int* __restrict__ bbase, int NB, int n,
                                                float* __restrict__ dinv,
                                                int* __restrict__ offs,
                                                int* __restrict__ csr) {
    __shared__ int cnt[BKT_W];
    __shared__ int s[BKT_W];
    __shared__ int cur[BKT_W];
    int t = threadIdx.x;
    int b = blockIdx.x;
    int nb0 = b << BKT_SHIFT;
    int wlen = min(BKT_W, n - nb0);
    int e0 = bbase[b], e1 = bbase[b + 1];

    cnt[t] = 0;
    __syncthreads();
    for (int e = e0 + t; e < e1; e += 256)
        atomicAdd(&cnt[bdst[e] - nb0], 1);
    __syncthreads();

    // exclusive scan of cnt
    int v = cnt[t];
    s[t] = v;
    __syncthreads();
    for (int off = 1; off < 256; off <<= 1) {
        int x = (t >= off) ? s[t - off] : 0;
        __syncthreads();
        s[t] += x;
        __syncthreads();
    }
    int myoff = e0 + s[t] - v;
    cur[t] = myoff;
    if (t < wlen) {
        offs[nb0 + t] = myoff;
        dinv[nb0 + t] = rsqrtf((float)(v + 1));   // in-degree + self loop
    }
    if (b == NB - 1 && t == 0) offs[n] = e1;
    __syncthreads();

    for (int e = e0 + t; e < e1; e += 256) {
        int d = bdst[e];
        int pos = atomicAdd(&cur[d - nb0], 1);
        csr[pos] = bsrc[e];
    }
}

// ---------------- fp32 -> bf16 (RTN-even) ----------------
__device__ __forceinline__ ushort_t f2bf(float f) {
    union { float f; uint32_t u; } a; a.f = f;
    uint32_t u = a.u;
    uint32_t r = (u + 0x7FFFu + ((u >> 16) & 1u)) >> 16;
    return (ushort_t)r;
}
__device__ __forceinline__ float bf_lo(uint32_t p) { return __uint_as_float(p << 16); }
__device__ __forceinline__ float bf_hi(uint32_t p) { return __uint_as_float(p & 0xFFFF0000u); }

// ---------------- GEMM: C[n x 128](bf16) = A[n x 128](f32) @ W[128 x 128](f32) ----------
#define COMP(v, i) ((i) == 0 ? (v).x : (i) == 1 ? (v).y : (i) == 2 ? (v).z : (v).w)

__global__ __launch_bounds__(256) void k_gemm128(const float* __restrict__ A,
                                                 const float* __restrict__ W,
                                                 ushort_t* __restrict__ C, int ntiles32) {
    __shared__ float wl[128 * 128];
    __shared__ float xl[32 * 128];
    int t = threadIdx.x;
#pragma unroll
    for (int i = 0; i < 16; i++)
        ((float4*)wl)[t + 256 * i] = ((const float4*)W)[t + 256 * i];

    int jg = t & 31;
    int rg = t >> 5;

    for (int tile = blockIdx.x; tile < ntiles32; tile += gridDim.x) {
        const float4* Ap = (const float4*)(A + (size_t)tile * 32 * 128);
        __syncthreads();
#pragma unroll
        for (int i = 0; i < 4; i++)
            ((float4*)xl)[t + 256 * i] = Ap[t + 256 * i];
        __syncthreads();

        float acc[4][4];
#pragma unroll
        for (int r = 0; r < 4; r++)
#pragma unroll
            for (int c = 0; c < 4; c++) acc[r][c] = 0.f;

        for (int kc = 0; kc < 128; kc += 4) {
            float4 xa[4], wb[4];
#pragma unroll
            for (int r = 0; r < 4; r++)
                xa[r] = ((const float4*)xl)[((rg * 4 + r) * 128 + kc) >> 2];
#pragma unroll
            for (int kk = 0; kk < 4; kk++)
                wb[kk] = ((const float4*)wl)[((kc + kk) * 128 + jg * 4) >> 2];
#pragma unroll
            for (int kk = 0; kk < 4; kk++) {
#pragma unroll
                for (int r = 0; r < 4; r++) {
                    float xv = COMP(xa[r], kk);
                    acc[r][0] = fmaf(xv, wb[kk].x, acc[r][0]);
                    acc[r][1] = fmaf(xv, wb[kk].y, acc[r][1]);
                    acc[r][2] = fmaf(xv, wb[kk].z, acc[r][2]);
                    acc[r][3] = fmaf(xv, wb[kk].w, acc[r][3]);
                }
            }
        }

#pragma unroll
        for (int r = 0; r < 4; r++) {
            ushort4 us;
            us.x = f2bf(acc[r][0]); us.y = f2bf(acc[r][1]);
            us.z = f2bf(acc[r][2]); us.w = f2bf(acc[r][3]);
            ((ushort4*)(C + ((size_t)tile * 32 + rg * 4 + r) * 128))[jg] = us;
        }
    }
}

// ---------------- Aggregation (wave-per-node, bf16 gather, fp32 accumulate) ----------------
__global__ __launch_bounds__(256) void k_agg(const ushort_t* __restrict__ xw,
                                             const int* __restrict__ offsets,
                                             const int* __restrict__ csr,
                                             const float* __restrict__ dinv,
                                             const float* __restrict__ bias,
                                             float* __restrict__ out, int n) {
    const int l = threadIdx.x & 63;
    const int wave = (blockIdx.x << 2) | (threadIdx.x >> 6);
    const int wstride = gridDim.x << 2;
    const float2 bb = ((const float2*)bias)[l];

    for (int v = wave; v < n; v += wstride) {
        float dv = dinv[v];
        uint32_t pv = ((const uint32_t*)(xw + (size_t)v * 128))[l];
        float ax = dv * bf_lo(pv);
        float ay = dv * bf_hi(pv);

        int e = offsets[v], e1 = offsets[v + 1];
        for (; e + 3 < e1; e += 4) {
            int u0 = csr[e], u1 = csr[e + 1], u2 = csr[e + 2], u3 = csr[e + 3];
            float d0 = dinv[u0], d1 = dinv[u1], d2 = dinv[u2], d3 = dinv[u3];
            uint32_t p0 = ((const uint32_t*)(xw + (size_t)u0 * 128))[l];
            uint32_t p1 = ((const uint32_t*)(xw + (size_t)u1 * 128))[l];
            uint32_t p2 = ((const uint32_t*)(xw + (size_t)u2 * 128))[l];
            uint32_t p3 = ((const uint32_t*)(xw + (size_t)u3 * 128))[l];
            ax = fmaf(d0, bf_lo(p0), ax); ay = fmaf(d0, bf_hi(p0), ay);
            ax = fmaf(d1, bf_lo(p1), ax); ay = fmaf(d1, bf_hi(p1), ay);
            ax = fmaf(d2, bf_lo(p2), ax); ay = fmaf(d2, bf_hi(p2), ay);
            ax = fmaf(d3, bf_lo(p3), ax); ay = fmaf(d3, bf_hi(p3), ay);
        }
        for (; e < e1; e++) {
            int u = csr[e];
            float du = dinv[u];
            uint32_t p = ((const uint32_t*)(xw + (size_t)u * 128))[l];
            ax = fmaf(du, bf_lo(p), ax); ay = fmaf(du, bf_hi(p), ay);
        }

        float2 o;
        o.x = fmaxf(fmaf(ax, dv, bb.x), 0.f);
        o.y = fmaxf(fmaf(ay, dv, bb.y), 0.f);
        ((float2*)(out + (size_t)v * 128))[l] = o;
    }
}

// ---------------- Mean pool + FC ----------------
__global__ __launch_bounds__(128) void k_pool(const float* __restrict__ h,
                                              float* __restrict__ pooled, int n) {
    int j = threadIdx.x;
    float local = 0.f;
    for (int r = blockIdx.x; r < n; r += gridDim.x)
        local += h[(size_t)r * 128 + j];
    atomicAdd(&pooled[j], local);
}

__global__ __launch_bounds__(128) void k_fc(const float* __restrict__ pooled,
                                            const float* __restrict__ Wfc,
                                            const float* __restrict__ bfc,
                                            float* __restrict__ out, float invN) {
    int j = threadIdx.x;
    float acc = bfc[j];
    for (int k = 0; k < 128; k++)
        acc = fmaf(pooled[k] * invN, Wfc[k * 128 + j], acc);
    out[j] = acc;
}

// ---------------- launcher ----------------
extern "C" void kernel_launch(void* const* d_in, const int* in_sizes, int n_in,
                              void* d_out, int out_size, void* d_ws, size_t ws_size,
                              hipStream_t stream) {
    const float* x    = (const float*)d_in[0];
    const int*   ei   = (const int*)d_in[1];
    const float* W1   = (const float*)d_in[2];
    const float* b1   = (const float*)d_in[3];
    const float* W2   = (const float*)d_in[4];
    const float* b2   = (const float*)d_in[5];
    const float* Wfc  = (const float*)d_in[6];
    const float* bfc  = (const float*)d_in[7];
    float*       out  = (float*)d_out;

    const int n = in_sizes[0] / 128;
    const int E = in_sizes[1] / 2;
    const int* src = ei;
    const int* dst = ei + E;
    const int NB = (n + BKT_W - 1) >> BKT_SHIFT;   // 391 for n=100000

    char* w = (char*)d_ws;
    ushort_t* xw = (ushort_t*)w; w += (size_t)n * 128 * sizeof(ushort_t);
    w = (char*)(((uintptr_t)w + 15) & ~(uintptr_t)15);
    float* h    = (float*)w;  w += (size_t)n * 128 * sizeof(float);
    int*   csr  = (int*)w;    w += (size_t)E * sizeof(int);
    int*   bsrc = (int*)w;    w += (size_t)E * sizeof(int);
    int*   bdst = (int*)w;    w += (size_t)E * sizeof(int);
    float* dinv = (float*)w;  w += (size_t)n * sizeof(float);
    int*   offs = (int*)w;    w += (size_t)(n + 1) * sizeof(int);
    w = (char*)(((uintptr_t)w + 15) & ~(uintptr_t)15);
    int*   bhist = (int*)w;   w += NB_MAX * sizeof(int);
    int*   bbase = (int*)w;   w += (NB_MAX + 1) * sizeof(int);
    int*   bcur  = (int*)w;   w += NB_MAX * sizeof(int);
    float* pooled = (float*)w; w += 128 * sizeof(float);

    k_zero<<<2, 256, 0, stream>>>(bhist, NB);
    k_zero<<<1, 128, 0, stream>>>((int*)pooled, 128);

    kA_hist<<<1024, 256, 0, stream>>>(dst, E, NB, bhist);
    kScanB<<<1, 512, 0, stream>>>(bhist, NB, E, bbase, bcur);
    kB_bucket<<<(E + KB_CHUNK - 1) / KB_CHUNK, 256, 0, stream>>>(src, dst, E, NB, bcur, bsrc, bdst);
    kC_build<<<NB, 256, 0, stream>>>(bsrc, bdst, bbase, NB, n, dinv, offs, csr);

    k_gemm128<<<512, 256, 0, stream>>>(x, W1, xw, n / 32);
    k_agg<<<8192, 256, 0, stream>>>(xw, offs, csr, dinv, b1, h, n);
    k_gemm128<<<512, 256, 0, stream>>>(h, W2, xw, n / 32);
    k_agg<<<8192, 256, 0, stream>>>(xw, offs, csr, dinv, b2, h, n);

    k_pool<<<512, 128, 0, stream>>>(h, pooled, n);
    k_fc<<<1, 128, 0, stream>>>(pooled, Wfc, bfc, out, 1.0f / (float)n);
}

// Round 5
// 462.813 us; speedup vs baseline: 1.9122x; 1.1165x over previous
//
#include <hip/hip_runtime.h>
#include <stdint.h>

typedef unsigned short ushort_t;
typedef __attribute__((ext_vector_type(8))) short bf16x8;   // 8 bf16 in 4 VGPRs
typedef __attribute__((ext_vector_type(4))) float f32x4;

#define BKT_SHIFT 8
#define BKT_W     256
#define NB_MAX    512
#define KB_ITERS  8
#define KB_CHUNK  (256 * KB_ITERS)

// ---------------- small helpers ----------------

__global__ void k_zero(int* __restrict__ p, int n) {
    int i = blockIdx.x * blockDim.x + threadIdx.x;
    if (i < n) p[i] = 0;
}

__device__ __forceinline__ ushort_t f2bf(float f) {
    union { float f; uint32_t u; } a; a.f = f;
    uint32_t u = a.u;
    uint32_t r = (u + 0x7FFFu + ((u >> 16) & 1u)) >> 16;
    return (ushort_t)r;
}
__device__ __forceinline__ float bf_lo(uint32_t p) { return __uint_as_float(p << 16); }
__device__ __forceinline__ float bf_hi(uint32_t p) { return __uint_as_float(p & 0xFFFF0000u); }

// Wt[n][k] = bf16(W[k][n]) for both layer weights (runs once per launch, tiny)
__global__ __launch_bounds__(256) void kW_conv(const float* __restrict__ W1,
                                               const float* __restrict__ W2,
                                               ushort_t* __restrict__ Wt1,
                                               ushort_t* __restrict__ Wt2) {
    int i = blockIdx.x * 256 + threadIdx.x;   // i < 16384
    int k = i >> 7, nn = i & 127;
    Wt1[nn * 128 + k] = f2bf(W1[i]);
    Wt2[nn * 128 + k] = f2bf(W2[i]);
}

// ---------------- CSR build (bucketed, from R4) ----------------

__global__ __launch_bounds__(256) void kA_hist(const int* __restrict__ dst, int E, int NB,
                                               int* __restrict__ bhist) {
    __shared__ int lh[NB_MAX];
    int t = threadIdx.x;
    for (int i = t; i < NB; i += 256) lh[i] = 0;
    __syncthreads();
    for (int e = blockIdx.x * 256 + t; e < E; e += gridDim.x * 256)
        atomicAdd(&lh[dst[e] >> BKT_SHIFT], 1);
    __syncthreads();
    for (int i = t; i < NB; i += 256)
        if (lh[i]) atomicAdd(&bhist[i], lh[i]);
}

__global__ __launch_bounds__(512) void kScanB(const int* __restrict__ bhist, int NB, int E,
                                              int* __restrict__ bbase, int* __restrict__ bcur) {
    __shared__ int s[512];
    int t = threadIdx.x;
    int v = (t < NB) ? bhist[t] : 0;
    s[t] = v;
    __syncthreads();
    for (int off = 1; off < 512; off <<= 1) {
        int x = (t >= off) ? s[t - off] : 0;
        __syncthreads();
        s[t] += x;
        __syncthreads();
    }
    if (t < NB) {
        int ex = s[t] - v;
        bbase[t] = ex;
        bcur[t]  = ex;
    }
    if (t == 0) bbase[NB] = E;
}

__global__ __launch_bounds__(256) void kB_bucket(const int* __restrict__ src,
                                                 const int* __restrict__ dst, int E, int NB,
                                                 int* __restrict__ bcur,
                                                 int* __restrict__ bsrc, int* __restrict__ bdst) {
    __shared__ int lh[NB_MAX];
    int t = threadIdx.x;
    for (int i = t; i < NB; i += 256) lh[i] = 0;
    __syncthreads();

    int base = blockIdx.x * KB_CHUNK;
    int dreg[KB_ITERS], rank[KB_ITERS];
#pragma unroll
    for (int i = 0; i < KB_ITERS; i++) {
        int e = base + t + i * 256;
        if (e < E) {
            int d = dst[e];
            dreg[i] = d;
            rank[i] = atomicAdd(&lh[d >> BKT_SHIFT], 1);
        } else {
            dreg[i] = -1; rank[i] = 0;
        }
    }
    __syncthreads();
    for (int i = t; i < NB; i += 256) {
        int c = lh[i];
        lh[i] = c ? atomicAdd(&bcur[i], c) : 0;
    }
    __syncthreads();
#pragma unroll
    for (int i = 0; i < KB_ITERS; i++) {
        int e = base + t + i * 256;
        if (dreg[i] >= 0) {
            int pos = lh[dreg[i] >> BKT_SHIFT] + rank[i];
            bdst[pos] = dreg[i];
            bsrc[pos] = src[e];
        }
    }
}

__global__ __launch_bounds__(256) void kC_build(const int* __restrict__ bsrc,
                                                const int* __restrict__ bdst,
                                                const int* __restrict__ bbase, int NB, int n,
                                                float* __restrict__ dinv,
                                                int* __restrict__ offs,
                                                int* __restrict__ csr) {
    __shared__ int cnt[BKT_W];
    __shared__ int s[BKT_W];
    __shared__ int cur[BKT_W];
    int t = threadIdx.x;
    int b = blockIdx.x;
    int nb0 = b << BKT_SHIFT;
    int wlen = min(BKT_W, n - nb0);
    int e0 = bbase[b], e1 = bbase[b + 1];

    cnt[t] = 0;
    __syncthreads();
    for (int e = e0 + t; e < e1; e += 256)
        atomicAdd(&cnt[bdst[e] - nb0], 1);
    __syncthreads();

    int v = cnt[t];
    s[t] = v;
    __syncthreads();
    for (int off = 1; off < 256; off <<= 1) {
        int x = (t >= off) ? s[t - off] : 0;
        __syncthreads();
        s[t] += x;
        __syncthreads();
    }
    int myoff = e0 + s[t] - v;
    cur[t] = myoff;
    if (t < wlen) {
        offs[nb0 + t] = myoff;
        dinv[nb0 + t] = rsqrtf((float)(v + 1));
    }
    if (b == NB - 1 && t == 0) offs[n] = e1;
    __syncthreads();

    for (int e = e0 + t; e < e1; e += 256) {
        int d = bdst[e];
        int pos = atomicAdd(&cur[d - nb0], 1);
        csr[pos] = bsrc[e];
    }
}

// ---------------- MFMA GEMM: C[n x 128](bf16, pre-scaled by dinv) ----------------
// C[r][c] = dinv[r] * sum_k A[r][k] * W[k][c];   Wt is W transposed [N][K] bf16.
// Block: 256 thr (4 waves), tile 64 rows; wave w computes rows w*16..w*16+15 x 128 cols.
// A-frag: lane holds A[m = l&15][k = (l>>4)*8 + j]; B-frag: B[k = (l>>4)*8 + j][n = l&15].
// C/D: col = l&15, row = (l>>4)*4 + reg  [verified m89].
template <bool AF32>
__global__ __launch_bounds__(256) void k_gemm_mfma(const void* __restrict__ Av,
                                                   const ushort_t* __restrict__ Wt,
                                                   const float* __restrict__ dinv,
                                                   ushort_t* __restrict__ C, int n) {
    __shared__ ushort_t al[64 * 136];    // A tile, +8 bf16 row pad
    __shared__ ushort_t wl[128 * 136];   // Wt, +8 bf16 row pad
    const int t = threadIdx.x;
    const int l = t & 63;
    const int wave = t >> 6;
    const int lane15 = l & 15;
    const int quad = l >> 4;
    const int m0 = blockIdx.x * 64;
    const int rows = min(64, n - m0);

    // stage Wt[128][128] -> wl
#pragma unroll
    for (int i = 0; i < 8; i++) {
        int f = t + 256 * i;
        int r = f >> 4, c = f & 15;
        *(uint4*)(&wl[r * 136 + c * 8]) = ((const uint4*)Wt)[f];
    }
    // stage A tile -> al (convert if fp32)
    if (AF32) {
        const float4* Ap = (const float4*)((const float*)Av + (size_t)m0 * 128);
        int nf = rows * 32;
#pragma unroll
        for (int i = 0; i < 8; i++) {
            int f = t + 256 * i;
            float4 v = make_float4(0.f, 0.f, 0.f, 0.f);
            if (f < nf) v = Ap[f];
            ushort4 us;
            us.x = f2bf(v.x); us.y = f2bf(v.y); us.z = f2bf(v.z); us.w = f2bf(v.w);
            int r = f >> 5, c = f & 31;
            *(ushort4*)(&al[r * 136 + c * 4]) = us;
        }
    } else {
        const uint4* Ap = (const uint4*)((const ushort_t*)Av + (size_t)m0 * 128);
        int nf = rows * 16;
#pragma unroll
        for (int i = 0; i < 4; i++) {
            int f = t + 256 * i;
            uint4 v = make_uint4(0, 0, 0, 0);
            if (f < nf) v = Ap[f];
            int r = f >> 4, c = f & 15;
            *(uint4*)(&al[r * 136 + c * 8]) = v;
        }
    }
    __syncthreads();

    f32x4 acc[8];
#pragma unroll
    for (int nt = 0; nt < 8; nt++) acc[nt] = (f32x4){0.f, 0.f, 0.f, 0.f};

    const int arow = wave * 16 + lane15;
#pragma unroll
    for (int kt = 0; kt < 4; kt++) {
        bf16x8 af = *(const bf16x8*)(&al[arow * 136 + kt * 32 + quad * 8]);
#pragma unroll
        for (int nt = 0; nt < 8; nt++) {
            bf16x8 bfr = *(const bf16x8*)(&wl[(nt * 16 + lane15) * 136 + kt * 32 + quad * 8]);
            acc[nt] = __builtin_amdgcn_mfma_f32_16x16x32_bf16(af, bfr, acc[nt], 0, 0, 0);
        }
    }

    const int rbase = m0 + wave * 16 + quad * 4;
    float dsc[4];
#pragma unroll
    for (int r = 0; r < 4; r++)
        dsc[r] = (rbase + r < n) ? dinv[rbase + r] : 0.f;
#pragma unroll
    for (int nt = 0; nt < 8; nt++)
#pragma unroll
        for (int r = 0; r < 4; r++) {
            int row = rbase + r;
            if (row < n) C[(size_t)row * 128 + nt * 16 + lane15] = f2bf(acc[nt][r] * dsc[r]);
        }
}

// ---------------- Aggregation: pure row-sum of pre-scaled xw' ----------------
// out[v] = bf16( relu( dinv[v] * (xw'[v] + sum_{u in N(v)} xw'[u]) + b ) )
__global__ __launch_bounds__(256) void k_agg(const ushort_t* __restrict__ xw,
                                             const int* __restrict__ offsets,
                                             const int* __restrict__ csr,
                                             const float* __restrict__ dinv,
                                             const float* __restrict__ bias,
                                             ushort_t* __restrict__ out, int n) {
    const int l = threadIdx.x & 63;
    const int wave = (blockIdx.x << 2) | (threadIdx.x >> 6);
    const int wstride = gridDim.x << 2;
    const float2 bb = ((const float2*)bias)[l];
    const uint32_t* xw32 = (const uint32_t*)xw;
    uint32_t* out32 = (uint32_t*)out;

    for (int v = wave; v < n; v += wstride) {
        uint32_t pv = xw32[(size_t)v * 64 + l];
        float ax = bf_lo(pv), ay = bf_hi(pv);

        int e  = __builtin_amdgcn_readfirstlane(offsets[v]);
        int e1 = __builtin_amdgcn_readfirstlane(offsets[v + 1]);
        for (; e + 7 < e1; e += 8) {
            uint32_t p[8];
#pragma unroll
            for (int i = 0; i < 8; i++) {
                int u = __builtin_amdgcn_readfirstlane(csr[e + i]);
                p[i] = xw32[(size_t)u * 64 + l];
            }
#pragma unroll
            for (int i = 0; i < 8; i++) { ax += bf_lo(p[i]); ay += bf_hi(p[i]); }
        }
        for (; e < e1; e++) {
            int u = __builtin_amdgcn_readfirstlane(csr[e]);
            uint32_t p = xw32[(size_t)u * 64 + l];
            ax += bf_lo(p); ay += bf_hi(p);
        }

        float dv = dinv[v];
        float ox = fmaxf(fmaf(ax, dv, bb.x), 0.f);
        float oy = fmaxf(fmaf(ay, dv, bb.y), 0.f);
        out32[(size_t)v * 64 + l] = ((uint32_t)f2bf(oy) << 16) | (uint32_t)f2bf(ox);
    }
}

// ---------------- Mean pool (bf16 in) + FC ----------------
__global__ __launch_bounds__(64) void k_pool(const ushort_t* __restrict__ h,
                                             float* __restrict__ pooled, int n) {
    int l = threadIdx.x;
    const uint32_t* h32 = (const uint32_t*)h;
    float sx = 0.f, sy = 0.f;
    for (int r = blockIdx.x; r < n; r += gridDim.x) {
        uint32_t p = h32[(size_t)r * 64 + l];
        sx += bf_lo(p); sy += bf_hi(p);
    }
    atomicAdd(&pooled[2 * l], sx);
    atomicAdd(&pooled[2 * l + 1], sy);
}

__global__ __launch_bounds__(128) void k_fc(const float* __restrict__ pooled,
                                            const float* __restrict__ Wfc,
                                            const float* __restrict__ bfc,
                                            float* __restrict__ out, float invN) {
    int j = threadIdx.x;
    float acc = bfc[j];
    for (int k = 0; k < 128; k++)
        acc = fmaf(pooled[k] * invN, Wfc[k * 128 + j], acc);
    out[j] = acc;
}

// ---------------- launcher ----------------
extern "C" void kernel_launch(void* const* d_in, const int* in_sizes, int n_in,
                              void* d_out, int out_size, void* d_ws, size_t ws_size,
                              hipStream_t stream) {
    const float* x    = (const float*)d_in[0];
    const int*   ei   = (const int*)d_in[1];
    const float* W1   = (const float*)d_in[2];
    const float* b1   = (const float*)d_in[3];
    const float* W2   = (const float*)d_in[4];
    const float* b2   = (const float*)d_in[5];
    const float* Wfc  = (const float*)d_in[6];
    const float* bfc  = (const float*)d_in[7];
    float*       out  = (float*)d_out;

    const int n = in_sizes[0] / 128;
    const int E = in_sizes[1] / 2;
    const int* src = ei;
    const int* dst = ei + E;
    const int NB = (n + BKT_W - 1) >> BKT_SHIFT;

    char* w = (char*)d_ws;
    ushort_t* xw = (ushort_t*)w; w += (size_t)n * 128 * sizeof(ushort_t);
    ushort_t* h  = (ushort_t*)w; w += (size_t)n * 128 * sizeof(ushort_t);
    int*   csr  = (int*)w;    w += (size_t)E * sizeof(int);
    int*   bsrc = (int*)w;    w += (size_t)E * sizeof(int);
    int*   bdst = (int*)w;    w += (size_t)E * sizeof(int);
    float* dinv = (float*)w;  w += (size_t)n * sizeof(float);
    int*   offs = (int*)w;    w += (size_t)(n + 1) * sizeof(int);
    w = (char*)(((uintptr_t)w + 15) & ~(uintptr_t)15);
    int*   bhist = (int*)w;   w += NB_MAX * sizeof(int);
    int*   bbase = (int*)w;   w += (NB_MAX + 1) * sizeof(int);
    int*   bcur  = (int*)w;   w += NB_MAX * sizeof(int);
    w = (char*)(((uintptr_t)w + 15) & ~(uintptr_t)15);
    float* pooled = (float*)w; w += 128 * sizeof(float);
    ushort_t* Wt1 = (ushort_t*)w; w += 16384 * sizeof(ushort_t);
    ushort_t* Wt2 = (ushort_t*)w; w += 16384 * sizeof(ushort_t);

    const int ntiles64 = (n + 63) / 64;

    k_zero<<<2, 256, 0, stream>>>(bhist, NB);
    k_zero<<<1, 128, 0, stream>>>((int*)pooled, 128);
    kW_conv<<<64, 256, 0, stream>>>(W1, W2, Wt1, Wt2);

    kA_hist<<<1024, 256, 0, stream>>>(dst, E, NB, bhist);
    kScanB<<<1, 512, 0, stream>>>(bhist, NB, E, bbase, bcur);
    kB_bucket<<<(E + KB_CHUNK - 1) / KB_CHUNK, 256, 0, stream>>>(src, dst, E, NB, bcur, bsrc, bdst);
    kC_build<<<NB, 256, 0, stream>>>(bsrc, bdst, bbase, NB, n, dinv, offs, csr);

    k_gemm_mfma<true><<<ntiles64, 256, 0, stream>>>(x, Wt1, dinv, xw, n);
    k_agg<<<8192, 256, 0, stream>>>(xw, offs, csr, dinv, b1, h, n);
    k_gemm_mfma<false><<<ntiles64, 256, 0, stream>>>(h, Wt2, dinv, xw, n);
    k_agg<<<8192, 256, 0, stream>>>(xw, offs, csr, dinv, b2, h, n);

    k_pool<<<512, 64, 0, stream>>>(h, pooled, n);
    k_fc<<<1, 128, 0, stream>>>(pooled, Wfc, bfc, out, 1.0f / (float)n);
}

// Round 6
// 412.425 us; speedup vs baseline: 2.1458x; 1.1222x over previous
//
#include <hip/hip_runtime.h>
#include <stdint.h>

typedef unsigned short ushort_t;
typedef __attribute__((ext_vector_type(8))) short bf16x8;   // 8 bf16 in 4 VGPRs
typedef __attribute__((ext_vector_type(4))) float f32x4;

#define BKT_SHIFT 8
#define BKT_W     256
#define NB_MAX    512
#define KB_ITERS  32
#define KB_CHUNK  (256 * KB_ITERS)   // 8192 edges per block

// ---------------- small helpers ----------------

__global__ void k_zero(int* __restrict__ p, int n) {
    int i = blockIdx.x * blockDim.x + threadIdx.x;
    if (i < n) p[i] = 0;
}

__device__ __forceinline__ ushort_t f2bf(float f) {
    union { float f; uint32_t u; } a; a.f = f;
    uint32_t u = a.u;
    uint32_t r = (u + 0x7FFFu + ((u >> 16) & 1u)) >> 16;
    return (ushort_t)r;
}
__device__ __forceinline__ float bf_lo(uint32_t p) { return __uint_as_float(p << 16); }
__device__ __forceinline__ float bf_hi(uint32_t p) { return __uint_as_float(p & 0xFFFF0000u); }

// Wt[n][k] = bf16(W[k][n]) for both layer weights
__global__ __launch_bounds__(256) void kW_conv(const float* __restrict__ W1,
                                               const float* __restrict__ W2,
                                               ushort_t* __restrict__ Wt1,
                                               ushort_t* __restrict__ Wt2) {
    int i = blockIdx.x * 256 + threadIdx.x;   // i < 16384
    int k = i >> 7, nn = i & 127;
    Wt1[nn * 128 + k] = f2bf(W1[i]);
    Wt2[nn * 128 + k] = f2bf(W2[i]);
}

// ---------------- CSR build (bucketed) ----------------

__global__ __launch_bounds__(256) void kA_hist(const int* __restrict__ dst, int E, int NB,
                                               int* __restrict__ bhist) {
    __shared__ int lh[NB_MAX];
    int t = threadIdx.x;
    for (int i = t; i < NB; i += 256) lh[i] = 0;
    __syncthreads();
    for (int e = blockIdx.x * 256 + t; e < E; e += gridDim.x * 256)
        atomicAdd(&lh[dst[e] >> BKT_SHIFT], 1);
    __syncthreads();
    for (int i = t; i < NB; i += 256)
        if (lh[i]) atomicAdd(&bhist[i], lh[i]);
}

__global__ __launch_bounds__(512) void kScanB(const int* __restrict__ bhist, int NB, int E,
                                              int* __restrict__ bbase, int* __restrict__ bcur) {
    __shared__ int s[512];
    int t = threadIdx.x;
    int v = (t < NB) ? bhist[t] : 0;
    s[t] = v;
    __syncthreads();
    for (int off = 1; off < 512; off <<= 1) {
        int x = (t >= off) ? s[t - off] : 0;
        __syncthreads();
        s[t] += x;
        __syncthreads();
    }
    if (t < NB) {
        int ex = s[t] - v;
        bbase[t] = ex;
        bcur[t]  = ex;
    }
    if (t == 0) bbase[NB] = E;
}

// scatter edges into bucket-ordered PACKED array: (src<<8) | (dst & 255)
__global__ __launch_bounds__(256) void kB_bucket(const int* __restrict__ src,
                                                 const int* __restrict__ dst, int E, int NB,
                                                 int* __restrict__ bcur,
                                                 uint32_t* __restrict__ bpack) {
    __shared__ int lh[NB_MAX];
    int t = threadIdx.x;
    for (int i = t; i < NB; i += 256) lh[i] = 0;
    __syncthreads();

    int base = blockIdx.x * KB_CHUNK;
    int dreg[KB_ITERS], rank[KB_ITERS];
#pragma unroll
    for (int i = 0; i < KB_ITERS; i++) {
        int e = base + t + i * 256;
        if (e < E) {
            int d = dst[e];
            dreg[i] = d;
            rank[i] = atomicAdd(&lh[d >> BKT_SHIFT], 1);
        } else {
            dreg[i] = -1; rank[i] = 0;
        }
    }
    __syncthreads();
    // reserve a contiguous global range per touched bucket
    for (int i = t; i < NB; i += 256) {
        int c = lh[i];
        lh[i] = c ? atomicAdd(&bcur[i], c) : 0;
    }
    __syncthreads();
#pragma unroll
    for (int i = 0; i < KB_ITERS; i++) {
        int e = base + t + i * 256;
        if (dreg[i] >= 0) {
            int d = dreg[i];
            int pos = lh[d >> BKT_SHIFT] + rank[i];
            bpack[pos] = ((uint32_t)src[e] << 8) | (uint32_t)(d & (BKT_W - 1));
        }
    }
}

// per-bucket fused count + scan + dinv + offs + csr fill (consumes packed edges)
__global__ __launch_bounds__(256) void kC_build(const uint32_t* __restrict__ bpack,
                                                const int* __restrict__ bbase, int NB, int n,
                                                float* __restrict__ dinv,
                                                int* __restrict__ offs,
                                                int* __restrict__ csr) {
    __shared__ int cnt[BKT_W];
    __shared__ int s[BKT_W];
    __shared__ int cur[BKT_W];
    int t = threadIdx.x;
    int b = blockIdx.x;
    int nb0 = b << BKT_SHIFT;
    int wlen = min(BKT_W, n - nb0);
    int e0 = bbase[b], e1 = bbase[b + 1];

    cnt[t] = 0;
    __syncthreads();
    for (int e = e0 + t; e < e1; e += 256)
        atomicAdd(&cnt[bpack[e] & (BKT_W - 1)], 1);
    __syncthreads();

    int v = cnt[t];
    s[t] = v;
    __syncthreads();
    for (int off = 1; off < 256; off <<= 1) {
        int x = (t >= off) ? s[t - off] : 0;
        __syncthreads();
        s[t] += x;
        __syncthreads();
    }
    int myoff = e0 + s[t] - v;
    cur[t] = myoff;
    if (t < wlen) {
        offs[nb0 + t] = myoff;
        dinv[nb0 + t] = rsqrtf((float)(v + 1));
    }
    if (b == NB - 1 && t == 0) offs[n] = e1;
    __syncthreads();

    for (int e = e0 + t; e < e1; e += 256) {
        uint32_t p = bpack[e];
        int pos = atomicAdd(&cur[p & (BKT_W - 1)], 1);
        csr[pos] = (int)(p >> 8);
    }
}

// ---------------- MFMA GEMM: C[n x 128](bf16, pre-scaled by dinv) ----------------
template <bool AF32>
__global__ __launch_bounds__(256) void k_gemm_mfma(const void* __restrict__ Av,
                                                   const ushort_t* __restrict__ Wt,
                                                   const float* __restrict__ dinv,
                                                   ushort_t* __restrict__ C, int n) {
    __shared__ ushort_t al[64 * 136];
    __shared__ ushort_t wl[128 * 136];
    const int t = threadIdx.x;
    const int l = t & 63;
    const int wave = t >> 6;
    const int lane15 = l & 15;
    const int quad = l >> 4;
    const int m0 = blockIdx.x * 64;
    const int rows = min(64, n - m0);

#pragma unroll
    for (int i = 0; i < 8; i++) {
        int f = t + 256 * i;
        int r = f >> 4, c = f & 15;
        *(uint4*)(&wl[r * 136 + c * 8]) = ((const uint4*)Wt)[f];
    }
    if (AF32) {
        const float4* Ap = (const float4*)((const float*)Av + (size_t)m0 * 128);
        int nf = rows * 32;
#pragma unroll
        for (int i = 0; i < 8; i++) {
            int f = t + 256 * i;
            float4 v = make_float4(0.f, 0.f, 0.f, 0.f);
            if (f < nf) v = Ap[f];
            ushort4 us;
            us.x = f2bf(v.x); us.y = f2bf(v.y); us.z = f2bf(v.z); us.w = f2bf(v.w);
            int r = f >> 5, c = f & 31;
            *(ushort4*)(&al[r * 136 + c * 4]) = us;
        }
    } else {
        const uint4* Ap = (const uint4*)((const ushort_t*)Av + (size_t)m0 * 128);
        int nf = rows * 16;
#pragma unroll
        for (int i = 0; i < 4; i++) {
            int f = t + 256 * i;
            uint4 v = make_uint4(0, 0, 0, 0);
            if (f < nf) v = Ap[f];
            int r = f >> 4, c = f & 15;
            *(uint4*)(&al[r * 136 + c * 8]) = v;
        }
    }
    __syncthreads();

    f32x4 acc[8];
#pragma unroll
    for (int nt = 0; nt < 8; nt++) acc[nt] = (f32x4){0.f, 0.f, 0.f, 0.f};

    const int arow = wave * 16 + lane15;
#pragma unroll
    for (int kt = 0; kt < 4; kt++) {
        bf16x8 af = *(const bf16x8*)(&al[arow * 136 + kt * 32 + quad * 8]);
#pragma unroll
        for (int nt = 0; nt < 8; nt++) {
            bf16x8 bfr = *(const bf16x8*)(&wl[(nt * 16 + lane15) * 136 + kt * 32 + quad * 8]);
            acc[nt] = __builtin_amdgcn_mfma_f32_16x16x32_bf16(af, bfr, acc[nt], 0, 0, 0);
        }
    }

    const int rbase = m0 + wave * 16 + quad * 4;
    float dsc[4];
#pragma unroll
    for (int r = 0; r < 4; r++)
        dsc[r] = (rbase + r < n) ? dinv[rbase + r] : 0.f;
#pragma unroll
    for (int nt = 0; nt < 8; nt++)
#pragma unroll
        for (int r = 0; r < 4; r++) {
            int row = rbase + r;
            if (row < n) C[(size_t)row * 128 + nt * 16 + lane15] = f2bf(acc[nt][r] * dsc[r]);
        }
}

// ---------------- Aggregation: pure row-sum of pre-scaled xw' ----------------
__global__ __launch_bounds__(256) void k_agg(const ushort_t* __restrict__ xw,
                                             const int* __restrict__ offsets,
                                             const int* __restrict__ csr,
                                             const float* __restrict__ dinv,
                                             const float* __restrict__ bias,
                                             ushort_t* __restrict__ out, int n) {
    const int l = threadIdx.x & 63;
    const int wave = (blockIdx.x << 2) | (threadIdx.x >> 6);
    const int wstride = gridDim.x << 2;
    const float2 bb = ((const float2*)bias)[l];
    const uint32_t* xw32 = (const uint32_t*)xw;
    uint32_t* out32 = (uint32_t*)out;

    for (int v = wave; v < n; v += wstride) {
        uint32_t pv = xw32[(size_t)v * 64 + l];
        float ax = bf_lo(pv), ay = bf_hi(pv);

        int e  = __builtin_amdgcn_readfirstlane(offsets[v]);
        int e1 = __builtin_amdgcn_readfirstlane(offsets[v + 1]);
        for (; e + 7 < e1; e += 8) {
            uint32_t p[8];
#pragma unroll
            for (int i = 0; i < 8; i++) {
                int u = __builtin_amdgcn_readfirstlane(csr[e + i]);
                p[i] = xw32[(size_t)u * 64 + l];
            }
#pragma unroll
            for (int i = 0; i < 8; i++) { ax += bf_lo(p[i]); ay += bf_hi(p[i]); }
        }
        for (; e < e1; e++) {
            int u = __builtin_amdgcn_readfirstlane(csr[e]);
            uint32_t p = xw32[(size_t)u * 64 + l];
            ax += bf_lo(p); ay += bf_hi(p);
        }

        float dv = dinv[v];
        float ox = fmaxf(fmaf(ax, dv, bb.x), 0.f);
        float oy = fmaxf(fmaf(ay, dv, bb.y), 0.f);
        out32[(size_t)v * 64 + l] = ((uint32_t)f2bf(oy) << 16) | (uint32_t)f2bf(ox);
    }
}

// ---------------- Mean pool (bf16 in, wave-per-span, block-reduced) ----------------
__global__ __launch_bounds__(256) void k_pool(const ushort_t* __restrict__ h,
                                              float* __restrict__ pooled, int n) {
    __shared__ float red[512];
    const int t = threadIdx.x;
    const int l = t & 63;
    const int wv = (blockIdx.x << 2) | (t >> 6);
    const int ws = gridDim.x << 2;
    const uint32_t* h32 = (const uint32_t*)h;

    const int span = (n + ws - 1) / ws;
    int r0 = wv * span;
    int r1 = min(n, r0 + span);
    float sx = 0.f, sy = 0.f;
    int r = r0;
    for (; r + 3 < r1; r += 4) {
        uint32_t p0 = h32[(size_t)r * 64 + l];
        uint32_t p1 = h32[(size_t)(r + 1) * 64 + l];
        uint32_t p2 = h32[(size_t)(r + 2) * 64 + l];
        uint32_t p3 = h32[(size_t)(r + 3) * 64 + l];
        sx += bf_lo(p0) + bf_lo(p1) + bf_lo(p2) + bf_lo(p3);
        sy += bf_hi(p0) + bf_hi(p1) + bf_hi(p2) + bf_hi(p3);
    }
    for (; r < r1; r++) {
        uint32_t p = h32[(size_t)r * 64 + l];
        sx += bf_lo(p); sy += bf_hi(p);
    }
    red[t] = sx;
    red[256 + t] = sy;
    __syncthreads();
    if (t < 64) {
        sx = red[t] + red[t + 64] + red[t + 128] + red[t + 192];
        sy = red[256 + t] + red[256 + t + 64] + red[256 + t + 128] + red[256 + t + 192];
        atomicAdd(&pooled[2 * l], sx);
        atomicAdd(&pooled[2 * l + 1], sy);
    }
}

__global__ __launch_bounds__(128) void k_fc(const float* __restrict__ pooled,
                                            const float* __restrict__ Wfc,
                                            const float* __restrict__ bfc,
                                            float* __restrict__ out, float invN) {
    int j = threadIdx.x;
    float acc = bfc[j];
    for (int k = 0; k < 128; k++)
        acc = fmaf(pooled[k] * invN, Wfc[k * 128 + j], acc);
    out[j] = acc;
}

// ---------------- launcher ----------------
extern "C" void kernel_launch(void* const* d_in, const int* in_sizes, int n_in,
                              void* d_out, int out_size, void* d_ws, size_t ws_size,
                              hipStream_t stream) {
    const float* x    = (const float*)d_in[0];
    const int*   ei   = (const int*)d_in[1];
    const float* W1   = (const float*)d_in[2];
    const float* b1   = (const float*)d_in[3];
    const float* W2   = (const float*)d_in[4];
    const float* b2   = (const float*)d_in[5];
    const float* Wfc  = (const float*)d_in[6];
    const float* bfc  = (const float*)d_in[7];
    float*       out  = (float*)d_out;

    const int n = in_sizes[0] / 128;
    const int E = in_sizes[1] / 2;
    const int* src = ei;
    const int* dst = ei + E;
    const int NB = (n + BKT_W - 1) >> BKT_SHIFT;

    char* w = (char*)d_ws;
    ushort_t* xw = (ushort_t*)w; w += (size_t)n * 128 * sizeof(ushort_t);
    ushort_t* h  = (ushort_t*)w; w += (size_t)n * 128 * sizeof(ushort_t);
    int*      csr   = (int*)w;      w += (size_t)E * sizeof(int);
    uint32_t* bpack = (uint32_t*)w; w += (size_t)E * sizeof(uint32_t);
    float* dinv = (float*)w;  w += (size_t)n * sizeof(float);
    int*   offs = (int*)w;    w += (size_t)(n + 1) * sizeof(int);
    w = (char*)(((uintptr_t)w + 15) & ~(uintptr_t)15);
    int*   bhist = (int*)w;   w += NB_MAX * sizeof(int);
    int*   bbase = (int*)w;   w += (NB_MAX + 1) * sizeof(int);
    int*   bcur  = (int*)w;   w += NB_MAX * sizeof(int);
    w = (char*)(((uintptr_t)w + 15) & ~(uintptr_t)15);
    float* pooled = (float*)w; w += 128 * sizeof(float);
    ushort_t* Wt1 = (ushort_t*)w; w += 16384 * sizeof(ushort_t);
    ushort_t* Wt2 = (ushort_t*)w; w += 16384 * sizeof(ushort_t);

    const int ntiles64 = (n + 63) / 64;

    k_zero<<<2, 256, 0, stream>>>(bhist, NB);
    k_zero<<<1, 128, 0, stream>>>((int*)pooled, 128);
    kW_conv<<<64, 256, 0, stream>>>(W1, W2, Wt1, Wt2);

    kA_hist<<<1024, 256, 0, stream>>>(dst, E, NB, bhist);
    kScanB<<<1, 512, 0, stream>>>(bhist, NB, E, bbase, bcur);
    kB_bucket<<<(E + KB_CHUNK - 1) / KB_CHUNK, 256, 0, stream>>>(src, dst, E, NB, bcur, bpack);
    kC_build<<<NB, 256, 0, stream>>>(bpack, bbase, NB, n, dinv, offs, csr);

    k_gemm_mfma<true><<<ntiles64, 256, 0, stream>>>(x, Wt1, dinv, xw, n);
    k_agg<<<8192, 256, 0, stream>>>(xw, offs, csr, dinv, b1, h, n);
    k_gemm_mfma<false><<<ntiles64, 256, 0, stream>>>(h, Wt2, dinv, xw, n);
    k_agg<<<8192, 256, 0, stream>>>(xw, offs, csr, dinv, b2, h, n);

    k_pool<<<1024, 256, 0, stream>>>(h, pooled, n);
    k_fc<<<1, 128, 0, stream>>>(pooled, Wfc, bfc, out, 1.0f / (float)n);
}